// Round 1
// baseline (2800.731 us; speedup 1.0000x reference)
//
#include <hip/hip_runtime.h>
#include <stdint.h>

#define M_NODES 100000
#define NUM_EDGES 3200000
#define IN_DIM 512
#define HIDDEN 256
#define NCLS 64

typedef __bf16 bf16x8 __attribute__((ext_vector_type(8)));
typedef float floatx4 __attribute__((ext_vector_type(4)));

// ---- workspace layout (bytes) ----
// row_ptr : int[100001]              @ 0         (400004 -> pad 400016)
// W1T bf16: ushort[256*512]          @ 400016    (262144)
// W2T bf16: ushort[64*256]           @ 662160    (32768)
// h1  bf16: ushort[100000*256]       @ 694928    (51200000)
// T_a fp32: float[100000*64]         @ 51894928  (25600000)
// T_b fp32: float[100000*64]         @ 77494928  (25600000)
#define WS_ROWPTR 0
#define WS_W1T    400016
#define WS_W2T    662160
#define WS_H1     694928
#define WS_TA     51894928
#define WS_TB     77494928

// ---------------- weight transpose + bf16 convert ----------------
__global__ __launch_bounds__(256) void prep_weights(
    const float* __restrict__ W1, const float* __restrict__ W2,
    unsigned short* __restrict__ w1t, unsigned short* __restrict__ w2t) {
  int tid = blockIdx.x * 256 + threadIdx.x;
  if (tid < IN_DIM * HIDDEN) {
    int n = tid >> 9;        // [0,256)
    int k = tid & 511;       // [0,512)
    __bf16 v = (__bf16)W1[k * HIDDEN + n];
    w1t[tid] = __builtin_bit_cast(unsigned short, v);
  } else {
    int idx = tid - IN_DIM * HIDDEN;
    if (idx < HIDDEN * NCLS) {
      int n = idx >> 8;      // [0,64)
      int k = idx & 255;     // [0,256)
      __bf16 v = (__bf16)W2[k * NCLS + n];
      w2t[idx] = __builtin_bit_cast(unsigned short, v);
    }
  }
}

// ---------------- row_ptr via binary search over sorted edge_row ----------------
__global__ __launch_bounds__(256) void build_rowptr(
    const int* __restrict__ erow, int* __restrict__ rp) {
  int r = blockIdx.x * 256 + threadIdx.x;
  if (r > M_NODES) return;
  if (r == M_NODES) { rp[r] = NUM_EDGES; return; }
  int lo = 0, hi = NUM_EDGES;
  while (lo < hi) {
    int mid = (lo + hi) >> 1;
    if (erow[mid] < r) lo = mid + 1; else hi = mid;
  }
  rp[r] = lo;
}

// ---------------- GEMM1: h1 = relu(x @ W1 + b1), bf16 out ----------------
// block = 256 thr (4 waves). Block covers 32 rows; wave w covers cols [w*64, w*64+64).
// grid = 100000/32 = 3125 (exact).
__global__ __launch_bounds__(256) void gemm1(
    const float* __restrict__ x, const unsigned short* __restrict__ w1t,
    const float* __restrict__ b1, unsigned short* __restrict__ h1) {
  const int wave = threadIdx.x >> 6, lane = threadIdx.x & 63;
  const int m0 = blockIdx.x * 32;
  const int n0 = wave * 64;
  const int l15 = lane & 15, quad = lane >> 4;

  floatx4 acc[2][4] = {};
  for (int kb = 0; kb < IN_DIM; kb += 32) {
    const int k = kb + quad * 8;
    bf16x8 afrag[2], bfrag[4];
#pragma unroll
    for (int tm = 0; tm < 2; tm++) {
      const float* ap = x + (size_t)(m0 + tm * 16 + l15) * IN_DIM + k;
      floatx4 a0 = *(const floatx4*)ap;
      floatx4 a1 = *(const floatx4*)(ap + 4);
      bf16x8 f;
      f[0] = (__bf16)a0[0]; f[1] = (__bf16)a0[1]; f[2] = (__bf16)a0[2]; f[3] = (__bf16)a0[3];
      f[4] = (__bf16)a1[0]; f[5] = (__bf16)a1[1]; f[6] = (__bf16)a1[2]; f[7] = (__bf16)a1[3];
      afrag[tm] = f;
    }
#pragma unroll
    for (int tn = 0; tn < 4; tn++) {
      const unsigned short* bp = w1t + (size_t)(n0 + tn * 16 + l15) * IN_DIM + k;
      bfrag[tn] = *(const bf16x8*)bp;
    }
#pragma unroll
    for (int tm = 0; tm < 2; tm++)
#pragma unroll
      for (int tn = 0; tn < 4; tn++)
        acc[tm][tn] = __builtin_amdgcn_mfma_f32_16x16x32_bf16(afrag[tm], bfrag[tn], acc[tm][tn], 0, 0, 0);
  }

#pragma unroll
  for (int tm = 0; tm < 2; tm++)
#pragma unroll
    for (int tn = 0; tn < 4; tn++) {
      const int col = n0 + tn * 16 + l15;
      const float bias = b1[col];
#pragma unroll
      for (int r = 0; r < 4; r++) {
        const int row = m0 + tm * 16 + quad * 4 + r;
        float v = acc[tm][tn][r] + bias;
        v = v > 0.0f ? v : 0.0f;
        __bf16 bv = (__bf16)v;
        h1[(size_t)row * HIDDEN + col] = __builtin_bit_cast(unsigned short, bv);
      }
    }
}

// ---------------- GEMM2: T0 = h1 @ W2 + b2, fp32 out ----------------
// wave covers 32 rows x 64 cols; block (4 waves) covers 128 rows. grid = 782.
__global__ __launch_bounds__(256) void gemm2(
    const unsigned short* __restrict__ h1, const unsigned short* __restrict__ w2t,
    const float* __restrict__ b2, float* __restrict__ t0) {
  const int wave = threadIdx.x >> 6, lane = threadIdx.x & 63;
  const int m0 = blockIdx.x * 128 + wave * 32;
  if (m0 >= M_NODES) return;  // M divisible by 32 -> whole-wave guard suffices
  const int l15 = lane & 15, quad = lane >> 4;

  floatx4 acc[2][4] = {};
  for (int kb = 0; kb < HIDDEN; kb += 32) {
    const int k = kb + quad * 8;
    bf16x8 afrag[2], bfrag[4];
#pragma unroll
    for (int tm = 0; tm < 2; tm++)
      afrag[tm] = *(const bf16x8*)(h1 + (size_t)(m0 + tm * 16 + l15) * HIDDEN + k);
#pragma unroll
    for (int tn = 0; tn < 4; tn++)
      bfrag[tn] = *(const bf16x8*)(w2t + (size_t)(tn * 16 + l15) * HIDDEN + k);
#pragma unroll
    for (int tm = 0; tm < 2; tm++)
#pragma unroll
      for (int tn = 0; tn < 4; tn++)
        acc[tm][tn] = __builtin_amdgcn_mfma_f32_16x16x32_bf16(afrag[tm], bfrag[tn], acc[tm][tn], 0, 0, 0);
  }

#pragma unroll
  for (int tm = 0; tm < 2; tm++)
#pragma unroll
    for (int tn = 0; tn < 4; tn++) {
      const int col = tn * 16 + l15;  // [0,64)
      const float bias = b2[col];
#pragma unroll
      for (int r = 0; r < 4; r++) {
        const int row = m0 + tm * 16 + quad * 4 + r;
        t0[(size_t)row * NCLS + col] = acc[tm][tn][r] + bias;
      }
    }
}

// ---------------- SpMM first: T1 = L T0 ; z = g0*T0 + g1*T1 ----------------
// one 64-lane team per row, lane = column. block 256 = 4 rows. grid = 25000.
__global__ __launch_bounds__(256) void spmm_first(
    const int* __restrict__ rp, const int* __restrict__ cols,
    const float* __restrict__ vals, const float* __restrict__ t0,
    float* __restrict__ t1, const float* __restrict__ gamma,
    float* __restrict__ z) {
  const int r = blockIdx.x * 4 + (threadIdx.x >> 6);
  const int c = threadIdx.x & 63;
  const int rs = rp[r], re = rp[r + 1];
  float acc = 0.0f;
  for (int e = rs; e < re; ++e) {
    acc += vals[e] * t0[(size_t)cols[e] * NCLS + c];
  }
  const size_t o = (size_t)r * NCLS + c;
  t1[o] = acc;
  z[o] = gamma[0] * t0[o] + gamma[1] * acc;
}

// ---------------- SpMM step: Tn = 2 L Tc - Tp (in-place into Tp); z += g[k]*Tn ----
__global__ __launch_bounds__(256) void spmm_step(
    const int* __restrict__ rp, const int* __restrict__ cols,
    const float* __restrict__ vals, const float* __restrict__ tc,
    float* __restrict__ tp, const float* __restrict__ gamma, int kidx,
    float* __restrict__ z) {
  const int r = blockIdx.x * 4 + (threadIdx.x >> 6);
  const int c = threadIdx.x & 63;
  const int rs = rp[r], re = rp[r + 1];
  float acc = 0.0f;
  for (int e = rs; e < re; ++e) {
    acc += vals[e] * tc[(size_t)cols[e] * NCLS + c];
  }
  const size_t o = (size_t)r * NCLS + c;
  const float tn = 2.0f * acc - tp[o];
  tp[o] = tn;
  z[o] += gamma[kidx] * tn;
}

extern "C" void kernel_launch(void* const* d_in, const int* in_sizes, int n_in,
                              void* d_out, int out_size, void* d_ws, size_t ws_size,
                              hipStream_t stream) {
  const float* x     = (const float*)d_in[0];
  const int*   erow  = (const int*)d_in[1];
  const int*   ecol  = (const int*)d_in[2];
  const float* evals = (const float*)d_in[3];
  const float* W1    = (const float*)d_in[4];
  const float* b1    = (const float*)d_in[5];
  const float* W2    = (const float*)d_in[6];
  const float* b2    = (const float*)d_in[7];
  const float* gamma = (const float*)d_in[8];

  char* ws = (char*)d_ws;
  int*            rp  = (int*)(ws + WS_ROWPTR);
  unsigned short* w1t = (unsigned short*)(ws + WS_W1T);
  unsigned short* w2t = (unsigned short*)(ws + WS_W2T);
  unsigned short* h1  = (unsigned short*)(ws + WS_H1);
  float*          ta  = (float*)(ws + WS_TA);
  float*          tb  = (float*)(ws + WS_TB);
  float*          z   = (float*)d_out;

  prep_weights<<<576, 256, 0, stream>>>(W1, W2, w1t, w2t);
  build_rowptr<<<(M_NODES + 256) / 256, 256, 0, stream>>>(erow, rp);
  gemm1<<<M_NODES / 32, 256, 0, stream>>>(x, w1t, b1, h1);
  gemm2<<<(M_NODES + 127) / 128, 256, 0, stream>>>(h1, w2t, b2, ta);

  spmm_first<<<M_NODES / 4, 256, 0, stream>>>(rp, ecol, evals, ta, tb, gamma, z);

  float* cur = tb;  // T_curr
  float* pd  = ta;  // T_prev (becomes T_next)
  for (int k = 2; k <= 8; ++k) {
    spmm_step<<<M_NODES / 4, 256, 0, stream>>>(rp, ecol, evals, cur, pd, gamma, k, z);
    float* t = cur; cur = pd; pd = t;
  }
}

// Round 2
// 1517.957 us; speedup vs baseline: 1.8451x; 1.8451x over previous
//
#include <hip/hip_runtime.h>
#include <stdint.h>

#define M_NODES 100000
#define NUM_EDGES 3200000
#define IN_DIM 512
#define HIDDEN 256
#define NCLS 64

typedef __bf16 bf16x8 __attribute__((ext_vector_type(8)));
typedef float floatx4 __attribute__((ext_vector_type(4)));

// ---- workspace layout (bytes) ----
// rp   : int[100001]            @ 0
// w1t  : ushort[256*512]        @ 400016
// w2t  : ushort[64*256]         @ 662160
// h1   : ushort[100000*256]     @ 694928     (dead after gemm2; bB aliases it)
// bB   : ushort[100000*64]      @ 694928     (alias of h1 — first written by spmm_first)
// fA   : float[100000*64]       @ 51894928
// fB   : float[100000*64]       @ 77494928
// bA   : ushort[100000*64]      @ 103094928
// total 115,894,928 bytes
#define WS_ROWPTR 0
#define WS_W1T    400016
#define WS_W2T    662160
#define WS_H1     694928
#define WS_BB     694928
#define WS_FA     51894928
#define WS_FB     77494928
#define WS_BA     103094928

// ---------------- weight transpose + bf16 convert ----------------
__global__ __launch_bounds__(256) void prep_weights(
    const float* __restrict__ W1, const float* __restrict__ W2,
    unsigned short* __restrict__ w1t, unsigned short* __restrict__ w2t) {
  int tid = blockIdx.x * 256 + threadIdx.x;
  if (tid < IN_DIM * HIDDEN) {
    int n = tid >> 9;
    int k = tid & 511;
    __bf16 v = (__bf16)W1[k * HIDDEN + n];
    w1t[tid] = __builtin_bit_cast(unsigned short, v);
  } else {
    int idx = tid - IN_DIM * HIDDEN;
    if (idx < HIDDEN * NCLS) {
      int n = idx >> 8;
      int k = idx & 255;
      __bf16 v = (__bf16)W2[k * NCLS + n];
      w2t[idx] = __builtin_bit_cast(unsigned short, v);
    }
  }
}

// ---------------- row_ptr via binary search over sorted edge_row ----------------
__global__ __launch_bounds__(256) void build_rowptr(
    const int* __restrict__ erow, int* __restrict__ rp) {
  int r = blockIdx.x * 256 + threadIdx.x;
  if (r > M_NODES) return;
  if (r == M_NODES) { rp[r] = NUM_EDGES; return; }
  int lo = 0, hi = NUM_EDGES;
  while (lo < hi) {
    int mid = (lo + hi) >> 1;
    if (erow[mid] < r) lo = mid + 1; else hi = mid;
  }
  rp[r] = lo;
}

// ---------------- GEMM1: h1 = relu(x @ W1 + b1), bf16 out ----------------
// Wave owns 32 rows x ALL 256 cols (acc[2][16]); block = 4 waves = 128 rows.
// x is read exactly once (205 MB HBM); W1^T (256 KB) stays L2-resident.
__global__ __launch_bounds__(256) void gemm1(
    const float* __restrict__ x, const unsigned short* __restrict__ w1t,
    const float* __restrict__ b1, unsigned short* __restrict__ h1) {
  const int wave = threadIdx.x >> 6, lane = threadIdx.x & 63;
  const int m0 = blockIdx.x * 128 + wave * 32;
  if (m0 >= M_NODES) return;  // M_NODES % 32 == 0: whole-wave guard
  const int l15 = lane & 15, quad = lane >> 4;

  floatx4 acc[2][16] = {};
  for (int kb = 0; kb < IN_DIM; kb += 32) {
    const int k = kb + quad * 8;
    bf16x8 afrag[2];
#pragma unroll
    for (int tm = 0; tm < 2; tm++) {
      const float* ap = x + (size_t)(m0 + tm * 16 + l15) * IN_DIM + k;
      floatx4 a0 = *(const floatx4*)ap;
      floatx4 a1 = *(const floatx4*)(ap + 4);
      bf16x8 f;
      f[0] = (__bf16)a0[0]; f[1] = (__bf16)a0[1]; f[2] = (__bf16)a0[2]; f[3] = (__bf16)a0[3];
      f[4] = (__bf16)a1[0]; f[5] = (__bf16)a1[1]; f[6] = (__bf16)a1[2]; f[7] = (__bf16)a1[3];
      afrag[tm] = f;
    }
#pragma unroll
    for (int tn = 0; tn < 16; tn++) {
      bf16x8 bfrag = *(const bf16x8*)(w1t + (size_t)(tn * 16 + l15) * IN_DIM + k);
      acc[0][tn] = __builtin_amdgcn_mfma_f32_16x16x32_bf16(afrag[0], bfrag, acc[0][tn], 0, 0, 0);
      acc[1][tn] = __builtin_amdgcn_mfma_f32_16x16x32_bf16(afrag[1], bfrag, acc[1][tn], 0, 0, 0);
    }
  }

#pragma unroll
  for (int tn = 0; tn < 16; tn++) {
    const int col = tn * 16 + l15;
    const float bias = b1[col];
#pragma unroll
    for (int tm = 0; tm < 2; tm++)
#pragma unroll
      for (int r = 0; r < 4; r++) {
        const int row = m0 + tm * 16 + quad * 4 + r;
        float v = acc[tm][tn][r] + bias;
        v = v > 0.0f ? v : 0.0f;
        __bf16 bv = (__bf16)v;
        h1[(size_t)row * HIDDEN + col] = __builtin_bit_cast(unsigned short, bv);
      }
  }
}

// ---------------- GEMM2: T0 = h1 @ W2 + b2 -> fp32 (fA) AND bf16 (bA) ----------------
__global__ __launch_bounds__(256) void gemm2(
    const unsigned short* __restrict__ h1, const unsigned short* __restrict__ w2t,
    const float* __restrict__ b2, float* __restrict__ t0f,
    unsigned short* __restrict__ t0b) {
  const int wave = threadIdx.x >> 6, lane = threadIdx.x & 63;
  const int m0 = blockIdx.x * 128 + wave * 32;
  if (m0 >= M_NODES) return;
  const int l15 = lane & 15, quad = lane >> 4;

  floatx4 acc[2][4] = {};
  for (int kb = 0; kb < HIDDEN; kb += 32) {
    const int k = kb + quad * 8;
    bf16x8 afrag[2], bfrag[4];
#pragma unroll
    for (int tm = 0; tm < 2; tm++)
      afrag[tm] = *(const bf16x8*)(h1 + (size_t)(m0 + tm * 16 + l15) * HIDDEN + k);
#pragma unroll
    for (int tn = 0; tn < 4; tn++)
      bfrag[tn] = *(const bf16x8*)(w2t + (size_t)(tn * 16 + l15) * HIDDEN + k);
#pragma unroll
    for (int tm = 0; tm < 2; tm++)
#pragma unroll
      for (int tn = 0; tn < 4; tn++)
        acc[tm][tn] = __builtin_amdgcn_mfma_f32_16x16x32_bf16(afrag[tm], bfrag[tn], acc[tm][tn], 0, 0, 0);
  }

#pragma unroll
  for (int tm = 0; tm < 2; tm++)
#pragma unroll
    for (int tn = 0; tn < 4; tn++) {
      const int col = tn * 16 + l15;
      const float bias = b2[col];
#pragma unroll
      for (int r = 0; r < 4; r++) {
        const int row = m0 + tm * 16 + quad * 4 + r;
        const float v = acc[tm][tn][r] + bias;
        t0f[(size_t)row * NCLS + col] = v;
        __bf16 bv = (__bf16)v;
        t0b[(size_t)row * NCLS + col] = __builtin_bit_cast(unsigned short, bv);
      }
    }
}

// ---------------- SpMM first: T1 = L T0 ; z = g0*T0 + g1*T1 ----------------
// one 64-lane team per row, lane = column; bf16 gathers, 8x unrolled for MLP.
__global__ __launch_bounds__(256) void spmm_first(
    const int* __restrict__ rp, const int* __restrict__ cols,
    const float* __restrict__ vals, const __bf16* __restrict__ t0b,
    const float* __restrict__ t0f, float* __restrict__ t1f,
    unsigned short* __restrict__ t1b, const float* __restrict__ gamma,
    float* __restrict__ z) {
  const int r = blockIdx.x * 4 + (threadIdx.x >> 6);
  const int c = threadIdx.x & 63;
  const int rs = rp[r], re = rp[r + 1];
  float a0 = 0, a1 = 0, a2 = 0, a3 = 0, a4 = 0, a5 = 0, a6 = 0, a7 = 0;
  int e = rs;
  const int e8 = rs + ((re - rs) & ~7);
  for (; e < e8; e += 8) {
    int c0 = cols[e+0], c1 = cols[e+1], c2 = cols[e+2], c3 = cols[e+3];
    int c4 = cols[e+4], c5 = cols[e+5], c6 = cols[e+6], c7 = cols[e+7];
    float g0 = (float)t0b[(size_t)c0 * NCLS + c];
    float g1 = (float)t0b[(size_t)c1 * NCLS + c];
    float g2 = (float)t0b[(size_t)c2 * NCLS + c];
    float g3 = (float)t0b[(size_t)c3 * NCLS + c];
    float g4 = (float)t0b[(size_t)c4 * NCLS + c];
    float g5 = (float)t0b[(size_t)c5 * NCLS + c];
    float g6 = (float)t0b[(size_t)c6 * NCLS + c];
    float g7 = (float)t0b[(size_t)c7 * NCLS + c];
    a0 += vals[e+0] * g0; a1 += vals[e+1] * g1;
    a2 += vals[e+2] * g2; a3 += vals[e+3] * g3;
    a4 += vals[e+4] * g4; a5 += vals[e+5] * g5;
    a6 += vals[e+6] * g6; a7 += vals[e+7] * g7;
  }
  for (; e < re; ++e)
    a0 += vals[e] * (float)t0b[(size_t)cols[e] * NCLS + c];
  const float acc = ((a0 + a1) + (a2 + a3)) + ((a4 + a5) + (a6 + a7));
  const size_t o = (size_t)r * NCLS + c;
  t1f[o] = acc;
  __bf16 bv = (__bf16)acc;
  t1b[o] = __builtin_bit_cast(unsigned short, bv);
  z[o] = gamma[0] * t0f[o] + gamma[1] * acc;
}

// ---------------- SpMM step: Tn = 2 L Tc - Tp (fp32, in place over Tp); z += g[k]*Tn ----
__global__ __launch_bounds__(256) void spmm_step(
    const int* __restrict__ rp, const int* __restrict__ cols,
    const float* __restrict__ vals, const __bf16* __restrict__ tcb,
    float* __restrict__ tpf, unsigned short* __restrict__ tnb,
    const float* __restrict__ gamma, int kidx, float* __restrict__ z) {
  const int r = blockIdx.x * 4 + (threadIdx.x >> 6);
  const int c = threadIdx.x & 63;
  const int rs = rp[r], re = rp[r + 1];
  float a0 = 0, a1 = 0, a2 = 0, a3 = 0, a4 = 0, a5 = 0, a6 = 0, a7 = 0;
  int e = rs;
  const int e8 = rs + ((re - rs) & ~7);
  for (; e < e8; e += 8) {
    int c0 = cols[e+0], c1 = cols[e+1], c2 = cols[e+2], c3 = cols[e+3];
    int c4 = cols[e+4], c5 = cols[e+5], c6 = cols[e+6], c7 = cols[e+7];
    float g0 = (float)tcb[(size_t)c0 * NCLS + c];
    float g1 = (float)tcb[(size_t)c1 * NCLS + c];
    float g2 = (float)tcb[(size_t)c2 * NCLS + c];
    float g3 = (float)tcb[(size_t)c3 * NCLS + c];
    float g4 = (float)tcb[(size_t)c4 * NCLS + c];
    float g5 = (float)tcb[(size_t)c5 * NCLS + c];
    float g6 = (float)tcb[(size_t)c6 * NCLS + c];
    float g7 = (float)tcb[(size_t)c7 * NCLS + c];
    a0 += vals[e+0] * g0; a1 += vals[e+1] * g1;
    a2 += vals[e+2] * g2; a3 += vals[e+3] * g3;
    a4 += vals[e+4] * g4; a5 += vals[e+5] * g5;
    a6 += vals[e+6] * g6; a7 += vals[e+7] * g7;
  }
  for (; e < re; ++e)
    a0 += vals[e] * (float)tcb[(size_t)cols[e] * NCLS + c];
  const float acc = ((a0 + a1) + (a2 + a3)) + ((a4 + a5) + (a6 + a7));
  const size_t o = (size_t)r * NCLS + c;
  const float tn = 2.0f * acc - tpf[o];
  tpf[o] = tn;
  __bf16 bv = (__bf16)tn;
  tnb[o] = __builtin_bit_cast(unsigned short, bv);
  z[o] += gamma[kidx] * tn;
}

extern "C" void kernel_launch(void* const* d_in, const int* in_sizes, int n_in,
                              void* d_out, int out_size, void* d_ws, size_t ws_size,
                              hipStream_t stream) {
  const float* x     = (const float*)d_in[0];
  const int*   erow  = (const int*)d_in[1];
  const int*   ecol  = (const int*)d_in[2];
  const float* evals = (const float*)d_in[3];
  const float* W1    = (const float*)d_in[4];
  const float* b1    = (const float*)d_in[5];
  const float* W2    = (const float*)d_in[6];
  const float* b2    = (const float*)d_in[7];
  const float* gamma = (const float*)d_in[8];

  char* ws = (char*)d_ws;
  int*            rp  = (int*)(ws + WS_ROWPTR);
  unsigned short* w1t = (unsigned short*)(ws + WS_W1T);
  unsigned short* w2t = (unsigned short*)(ws + WS_W2T);
  unsigned short* h1  = (unsigned short*)(ws + WS_H1);
  float*          fA  = (float*)(ws + WS_FA);
  float*          fB  = (float*)(ws + WS_FB);
  unsigned short* bA  = (unsigned short*)(ws + WS_BA);
  unsigned short* bB  = (unsigned short*)(ws + WS_BB);  // aliases h1 (dead after gemm2)
  float*          z   = (float*)d_out;

  prep_weights<<<576, 256, 0, stream>>>(W1, W2, w1t, w2t);
  build_rowptr<<<(M_NODES + 256) / 256, 256, 0, stream>>>(erow, rp);
  gemm1<<<(M_NODES + 127) / 128, 256, 0, stream>>>(x, w1t, b1, h1);
  gemm2<<<(M_NODES + 127) / 128, 256, 0, stream>>>(h1, w2t, b2, fA, bA);

  // T0: fp32 in fA, bf16 in bA.  T1 -> fp32 fB, bf16 bB (bB aliases now-dead h1).
  spmm_first<<<M_NODES / 4, 256, 0, stream>>>(rp, ecol, evals, (const __bf16*)bA,
                                              fA, fB, bB, gamma, z);

  // State: gather-src bf16 = bB (T1); fp32 prev = fA (T0); next writes -> fA, bA.
  float*          fprev = fA;
  float*          fothr = fB;
  unsigned short* bcur  = bB;
  unsigned short* bnext = bA;
  for (int k = 2; k <= 8; ++k) {
    spmm_step<<<M_NODES / 4, 256, 0, stream>>>(rp, ecol, evals, (const __bf16*)bcur,
                                               fprev, bnext, gamma, k, z);
    float* tf = fprev; fprev = fothr; fothr = tf;
    unsigned short* tb = bcur; bcur = bnext; bnext = tb;
  }
}

// Round 3
// 1430.549 us; speedup vs baseline: 1.9578x; 1.0611x over previous
//
#include <hip/hip_runtime.h>
#include <stdint.h>

#define M_NODES 100000
#define NUM_EDGES 3200000
#define IN_DIM 512
#define HIDDEN 256
#define NCLS 64

typedef __bf16 bf16x8 __attribute__((ext_vector_type(8)));
typedef float floatx4 __attribute__((ext_vector_type(4)));

// ---- workspace layout (bytes) ----
// rp   : int[100001]            @ 0
// w1t  : ushort[256*512]        @ 400016
// w2t  : ushort[64*256]         @ 662160
// h1   : ushort[100000*256]     @ 694928     (dead after gemm2; bB aliases it)
// bB   : ushort[100000*64]      @ 694928     (alias of h1)
// fA   : float[100000*64]       @ 51894928
// fB   : float[100000*64]       @ 77494928
// bA   : ushort[100000*64]      @ 103094928
// total 115,894,928 bytes
#define WS_ROWPTR 0
#define WS_W1T    400016
#define WS_W2T    662160
#define WS_H1     694928
#define WS_BB     694928
#define WS_FA     51894928
#define WS_FB     77494928
#define WS_BA     103094928

// ---------------- weight transpose + bf16 convert ----------------
__global__ __launch_bounds__(256) void prep_weights(
    const float* __restrict__ W1, const float* __restrict__ W2,
    unsigned short* __restrict__ w1t, unsigned short* __restrict__ w2t) {
  int tid = blockIdx.x * 256 + threadIdx.x;
  if (tid < IN_DIM * HIDDEN) {
    int n = tid >> 9;
    int k = tid & 511;
    __bf16 v = (__bf16)W1[k * HIDDEN + n];
    w1t[tid] = __builtin_bit_cast(unsigned short, v);
  } else {
    int idx = tid - IN_DIM * HIDDEN;
    if (idx < HIDDEN * NCLS) {
      int n = idx >> 8;
      int k = idx & 255;
      __bf16 v = (__bf16)W2[k * NCLS + n];
      w2t[idx] = __builtin_bit_cast(unsigned short, v);
    }
  }
}

// ---------------- row_ptr via binary search over sorted edge_row ----------------
__global__ __launch_bounds__(256) void build_rowptr(
    const int* __restrict__ erow, int* __restrict__ rp) {
  int r = blockIdx.x * 256 + threadIdx.x;
  if (r > M_NODES) return;
  if (r == M_NODES) { rp[r] = NUM_EDGES; return; }
  int lo = 0, hi = NUM_EDGES;
  while (lo < hi) {
    int mid = (lo + hi) >> 1;
    if (erow[mid] < r) lo = mid + 1; else hi = mid;
  }
  rp[r] = lo;
}

// ---------------- GEMM1: h1 = relu(x @ W1 + b1), bf16 out ----------------
// Block = 32 rows; 4 waves each own a 64-col slice (acc[2][4] = 32 AGPRs).
// K unrolled by 64: 16 independent 16B loads in flight per iteration.
// grid = 100000/32 = 3125 (exact).
__global__ __launch_bounds__(256) void gemm1(
    const float* __restrict__ x, const unsigned short* __restrict__ w1t,
    const float* __restrict__ b1, unsigned short* __restrict__ h1) {
  const int wave = threadIdx.x >> 6, lane = threadIdx.x & 63;
  const int m0 = blockIdx.x * 32;
  const int n0 = wave * 64;
  const int l15 = lane & 15, quad = lane >> 4;

  floatx4 acc[2][4] = {};
  for (int kb = 0; kb < IN_DIM; kb += 64) {
    bf16x8 afrag[2][2];  // [ksub][tm]
    bf16x8 bfrag[2][4];  // [ksub][tn]
#pragma unroll
    for (int ks = 0; ks < 2; ks++) {
      const int k = kb + ks * 32 + quad * 8;
#pragma unroll
      for (int tm = 0; tm < 2; tm++) {
        const float* ap = x + (size_t)(m0 + tm * 16 + l15) * IN_DIM + k;
        floatx4 a0 = *(const floatx4*)ap;
        floatx4 a1 = *(const floatx4*)(ap + 4);
        bf16x8 f;
        f[0] = (__bf16)a0[0]; f[1] = (__bf16)a0[1]; f[2] = (__bf16)a0[2]; f[3] = (__bf16)a0[3];
        f[4] = (__bf16)a1[0]; f[5] = (__bf16)a1[1]; f[6] = (__bf16)a1[2]; f[7] = (__bf16)a1[3];
        afrag[ks][tm] = f;
      }
#pragma unroll
      for (int tn = 0; tn < 4; tn++)
        bfrag[ks][tn] = *(const bf16x8*)(w1t + (size_t)(n0 + tn * 16 + l15) * IN_DIM + k);
    }
#pragma unroll
    for (int ks = 0; ks < 2; ks++)
#pragma unroll
      for (int tm = 0; tm < 2; tm++)
#pragma unroll
        for (int tn = 0; tn < 4; tn++)
          acc[tm][tn] = __builtin_amdgcn_mfma_f32_16x16x32_bf16(afrag[ks][tm], bfrag[ks][tn], acc[tm][tn], 0, 0, 0);
  }

#pragma unroll
  for (int tm = 0; tm < 2; tm++)
#pragma unroll
    for (int tn = 0; tn < 4; tn++) {
      const int col = n0 + tn * 16 + l15;
      const float bias = b1[col];
#pragma unroll
      for (int r = 0; r < 4; r++) {
        const int row = m0 + tm * 16 + quad * 4 + r;
        float v = acc[tm][tn][r] + bias;
        v = v > 0.0f ? v : 0.0f;
        __bf16 bv = (__bf16)v;
        h1[(size_t)row * HIDDEN + col] = __builtin_bit_cast(unsigned short, bv);
      }
    }
}

// ---------------- GEMM2: T0 = h1 @ W2 + b2 -> fp32 (fA) AND bf16 (bA) ----------------
__global__ __launch_bounds__(256) void gemm2(
    const unsigned short* __restrict__ h1, const unsigned short* __restrict__ w2t,
    const float* __restrict__ b2, float* __restrict__ t0f,
    unsigned short* __restrict__ t0b) {
  const int wave = threadIdx.x >> 6, lane = threadIdx.x & 63;
  const int m0 = blockIdx.x * 128 + wave * 32;
  if (m0 >= M_NODES) return;
  const int l15 = lane & 15, quad = lane >> 4;

  floatx4 acc[2][4] = {};
  for (int kb = 0; kb < HIDDEN; kb += 32) {
    const int k = kb + quad * 8;
    bf16x8 afrag[2], bfrag[4];
#pragma unroll
    for (int tm = 0; tm < 2; tm++)
      afrag[tm] = *(const bf16x8*)(h1 + (size_t)(m0 + tm * 16 + l15) * HIDDEN + k);
#pragma unroll
    for (int tn = 0; tn < 4; tn++)
      bfrag[tn] = *(const bf16x8*)(w2t + (size_t)(tn * 16 + l15) * HIDDEN + k);
#pragma unroll
    for (int tm = 0; tm < 2; tm++)
#pragma unroll
      for (int tn = 0; tn < 4; tn++)
        acc[tm][tn] = __builtin_amdgcn_mfma_f32_16x16x32_bf16(afrag[tm], bfrag[tn], acc[tm][tn], 0, 0, 0);
  }

#pragma unroll
  for (int tm = 0; tm < 2; tm++)
#pragma unroll
    for (int tn = 0; tn < 4; tn++) {
      const int col = tn * 16 + l15;
      const float bias = b2[col];
#pragma unroll
      for (int r = 0; r < 4; r++) {
        const int row = m0 + tm * 16 + quad * 4 + r;
        const float v = acc[tm][tn][r] + bias;
        t0f[(size_t)row * NCLS + col] = v;
        __bf16 bv = (__bf16)v;
        t0b[(size_t)row * NCLS + col] = __builtin_bit_cast(unsigned short, bv);
      }
    }
}

// ---------------- SpMM first: T1 = L T0 ; z = g0*T0 + g1*T1 ----------------
__global__ __launch_bounds__(256) void spmm_first(
    const int* __restrict__ rp, const int* __restrict__ cols,
    const float* __restrict__ vals, const __bf16* __restrict__ t0b,
    const float* __restrict__ t0f, float* __restrict__ t1f,
    unsigned short* __restrict__ t1b, const float* __restrict__ gamma,
    float* __restrict__ z) {
  const int r = blockIdx.x * 4 + (threadIdx.x >> 6);
  const int c = threadIdx.x & 63;
  const int rs = rp[r], re = rp[r + 1];
  float a0 = 0, a1 = 0, a2 = 0, a3 = 0, a4 = 0, a5 = 0, a6 = 0, a7 = 0;
  int e = rs;
  const int e8 = rs + ((re - rs) & ~7);
  for (; e < e8; e += 8) {
    int c0 = cols[e+0], c1 = cols[e+1], c2 = cols[e+2], c3 = cols[e+3];
    int c4 = cols[e+4], c5 = cols[e+5], c6 = cols[e+6], c7 = cols[e+7];
    float g0 = (float)t0b[(size_t)c0 * NCLS + c];
    float g1 = (float)t0b[(size_t)c1 * NCLS + c];
    float g2 = (float)t0b[(size_t)c2 * NCLS + c];
    float g3 = (float)t0b[(size_t)c3 * NCLS + c];
    float g4 = (float)t0b[(size_t)c4 * NCLS + c];
    float g5 = (float)t0b[(size_t)c5 * NCLS + c];
    float g6 = (float)t0b[(size_t)c6 * NCLS + c];
    float g7 = (float)t0b[(size_t)c7 * NCLS + c];
    a0 += vals[e+0] * g0; a1 += vals[e+1] * g1;
    a2 += vals[e+2] * g2; a3 += vals[e+3] * g3;
    a4 += vals[e+4] * g4; a5 += vals[e+5] * g5;
    a6 += vals[e+6] * g6; a7 += vals[e+7] * g7;
  }
  for (; e < re; ++e)
    a0 += vals[e] * (float)t0b[(size_t)cols[e] * NCLS + c];
  const float acc = ((a0 + a1) + (a2 + a3)) + ((a4 + a5) + (a6 + a7));
  const size_t o = (size_t)r * NCLS + c;
  t1f[o] = acc;
  __bf16 bv = (__bf16)acc;
  t1b[o] = __builtin_bit_cast(unsigned short, bv);
  z[o] = gamma[0] * t0f[o] + gamma[1] * acc;
}

// ---------------- SpMM step: Tn = 2 L Tc - Tp (fp32, in place over Tp); z += g[k]*Tn ----
__global__ __launch_bounds__(256) void spmm_step(
    const int* __restrict__ rp, const int* __restrict__ cols,
    const float* __restrict__ vals, const __bf16* __restrict__ tcb,
    float* __restrict__ tpf, unsigned short* __restrict__ tnb,
    const float* __restrict__ gamma, int kidx, float* __restrict__ z) {
  const int r = blockIdx.x * 4 + (threadIdx.x >> 6);
  const int c = threadIdx.x & 63;
  const int rs = rp[r], re = rp[r + 1];
  float a0 = 0, a1 = 0, a2 = 0, a3 = 0, a4 = 0, a5 = 0, a6 = 0, a7 = 0;
  int e = rs;
  const int e8 = rs + ((re - rs) & ~7);
  for (; e < e8; e += 8) {
    int c0 = cols[e+0], c1 = cols[e+1], c2 = cols[e+2], c3 = cols[e+3];
    int c4 = cols[e+4], c5 = cols[e+5], c6 = cols[e+6], c7 = cols[e+7];
    float g0 = (float)tcb[(size_t)c0 * NCLS + c];
    float g1 = (float)tcb[(size_t)c1 * NCLS + c];
    float g2 = (float)tcb[(size_t)c2 * NCLS + c];
    float g3 = (float)tcb[(size_t)c3 * NCLS + c];
    float g4 = (float)tcb[(size_t)c4 * NCLS + c];
    float g5 = (float)tcb[(size_t)c5 * NCLS + c];
    float g6 = (float)tcb[(size_t)c6 * NCLS + c];
    float g7 = (float)tcb[(size_t)c7 * NCLS + c];
    a0 += vals[e+0] * g0; a1 += vals[e+1] * g1;
    a2 += vals[e+2] * g2; a3 += vals[e+3] * g3;
    a4 += vals[e+4] * g4; a5 += vals[e+5] * g5;
    a6 += vals[e+6] * g6; a7 += vals[e+7] * g7;
  }
  for (; e < re; ++e)
    a0 += vals[e] * (float)tcb[(size_t)cols[e] * NCLS + c];
  const float acc = ((a0 + a1) + (a2 + a3)) + ((a4 + a5) + (a6 + a7));
  const size_t o = (size_t)r * NCLS + c;
  const float tn = 2.0f * acc - tpf[o];
  tpf[o] = tn;
  __bf16 bv = (__bf16)tn;
  tnb[o] = __builtin_bit_cast(unsigned short, bv);
  z[o] += gamma[kidx] * tn;
}

extern "C" void kernel_launch(void* const* d_in, const int* in_sizes, int n_in,
                              void* d_out, int out_size, void* d_ws, size_t ws_size,
                              hipStream_t stream) {
  const float* x     = (const float*)d_in[0];
  const int*   erow  = (const int*)d_in[1];
  const int*   ecol  = (const int*)d_in[2];
  const float* evals = (const float*)d_in[3];
  const float* W1    = (const float*)d_in[4];
  const float* b1    = (const float*)d_in[5];
  const float* W2    = (const float*)d_in[6];
  const float* b2    = (const float*)d_in[7];
  const float* gamma = (const float*)d_in[8];

  char* ws = (char*)d_ws;
  int*            rp  = (int*)(ws + WS_ROWPTR);
  unsigned short* w1t = (unsigned short*)(ws + WS_W1T);
  unsigned short* w2t = (unsigned short*)(ws + WS_W2T);
  unsigned short* h1  = (unsigned short*)(ws + WS_H1);
  float*          fA  = (float*)(ws + WS_FA);
  float*          fB  = (float*)(ws + WS_FB);
  unsigned short* bA  = (unsigned short*)(ws + WS_BA);
  unsigned short* bB  = (unsigned short*)(ws + WS_BB);  // aliases h1 (dead after gemm2)
  float*          z   = (float*)d_out;

  prep_weights<<<576, 256, 0, stream>>>(W1, W2, w1t, w2t);
  build_rowptr<<<(M_NODES + 256) / 256, 256, 0, stream>>>(erow, rp);
  gemm1<<<M_NODES / 32, 256, 0, stream>>>(x, w1t, b1, h1);
  gemm2<<<(M_NODES + 127) / 128, 256, 0, stream>>>(h1, w2t, b2, fA, bA);

  // T0: fp32 in fA, bf16 in bA.  T1 -> fp32 fB, bf16 bB (bB aliases now-dead h1).
  spmm_first<<<M_NODES / 4, 256, 0, stream>>>(rp, ecol, evals, (const __bf16*)bA,
                                              fA, fB, bB, gamma, z);

  float*          fprev = fA;
  float*          fothr = fB;
  unsigned short* bcur  = bB;
  unsigned short* bnext = bA;
  for (int k = 2; k <= 8; ++k) {
    spmm_step<<<M_NODES / 4, 256, 0, stream>>>(rp, ecol, evals, (const __bf16*)bcur,
                                               fprev, bnext, gamma, k, z);
    float* tf = fprev; fprev = fothr; fothr = tf;
    unsigned short* tb = bcur; bcur = bnext; bnext = tb;
  }
}

// Round 5
// 1367.330 us; speedup vs baseline: 2.0483x; 1.0462x over previous
//
#include <hip/hip_runtime.h>
#include <stdint.h>

#define M_NODES 100000
#define NUM_EDGES 3200000
#define IN_DIM 512
#define HIDDEN 256
#define NCLS 64

typedef __bf16 bf16x8 __attribute__((ext_vector_type(8)));
typedef float floatx4 __attribute__((ext_vector_type(4)));

// ---- workspace layout (bytes) ----
// rp   : int[100001]            @ 0
// w1t  : ushort[256*512]        @ 400016
// w2t  : ushort[64*256]         @ 662160
// h1   : ushort[100000*256]     @ 694928     (dead after gemm2; bB aliases it)
// bB   : ushort[100000*64]      @ 694928     (alias of h1)
// fA   : float[100000*64]       @ 51894928
// fB   : float[100000*64]       @ 77494928
// bA   : ushort[100000*64]      @ 103094928
#define WS_ROWPTR 0
#define WS_W1T    400016
#define WS_W2T    662160
#define WS_H1     694928
#define WS_BB     694928
#define WS_FA     51894928
#define WS_FB     77494928
#define WS_BA     103094928

// ---------------- weight transpose + bf16 convert ----------------
__global__ __launch_bounds__(256) void prep_weights(
    const float* __restrict__ W1, const float* __restrict__ W2,
    unsigned short* __restrict__ w1t, unsigned short* __restrict__ w2t) {
  int tid = blockIdx.x * 256 + threadIdx.x;
  if (tid < IN_DIM * HIDDEN) {
    int n = tid >> 9;
    int k = tid & 511;
    __bf16 v = (__bf16)W1[k * HIDDEN + n];
    w1t[tid] = __builtin_bit_cast(unsigned short, v);
  } else {
    int idx = tid - IN_DIM * HIDDEN;
    if (idx < HIDDEN * NCLS) {
      int n = idx >> 8;
      int k = idx & 255;
      __bf16 v = (__bf16)W2[k * NCLS + n];
      w2t[idx] = __builtin_bit_cast(unsigned short, v);
    }
  }
}

// ---------------- row_ptr via binary search over sorted edge_row ----------------
__global__ __launch_bounds__(256) void build_rowptr(
    const int* __restrict__ erow, int* __restrict__ rp) {
  int r = blockIdx.x * 256 + threadIdx.x;
  if (r > M_NODES) return;
  if (r == M_NODES) { rp[r] = NUM_EDGES; return; }
  int lo = 0, hi = NUM_EDGES;
  while (lo < hi) {
    int mid = (lo + hi) >> 1;
    if (erow[mid] < r) lo = mid + 1; else hi = mid;
  }
  rp[r] = lo;
}

// ---------------- GEMM1: h1 = relu(x @ W1 + b1), bf16 out ----------------
// Block = 32 rows; 4 waves split N into 64-col slices (acc[2][4] = 32 AGPRs).
// x tile (32 rows x 64 k fp32) staged in LDS with fully-coalesced float4 loads;
// padded row stride 68 floats -> <=2-way bank conflicts on ds_read_b128.
__global__ __launch_bounds__(256) void gemm1(
    const float* __restrict__ x, const unsigned short* __restrict__ w1t,
    const float* __restrict__ b1, unsigned short* __restrict__ h1) {
  __shared__ float xs[32 * 68];
  const int wave = threadIdx.x >> 6, lane = threadIdx.x & 63;
  const int m0 = blockIdx.x * 32;
  const int n0 = wave * 64;
  const int l15 = lane & 15, quad = lane >> 4;
  const int t = threadIdx.x;

  floatx4 acc[2][4] = {};
  for (int kb = 0; kb < IN_DIM; kb += 64) {
    __syncthreads();
#pragma unroll
    for (int j = 0; j < 2; j++) {
      const int i = t * 2 + j;      // 0..511
      const int row = i >> 4;       // 0..31
      const int kq = i & 15;        // float4 index within row
      floatx4 v = *(const floatx4*)(x + (size_t)(m0 + row) * IN_DIM + kb + kq * 4);
      *(floatx4*)(xs + row * 68 + kq * 4) = v;
    }
    __syncthreads();

    bf16x8 afrag[2][2];
    bf16x8 bfrag[2][4];
#pragma unroll
    for (int ks = 0; ks < 2; ks++) {
#pragma unroll
      for (int tm = 0; tm < 2; tm++) {
        const float* p = xs + (tm * 16 + l15) * 68 + ks * 32 + quad * 8;
        floatx4 a0 = *(const floatx4*)p;
        floatx4 a1 = *(const floatx4*)(p + 4);
        bf16x8 f;
        f[0] = (__bf16)a0[0]; f[1] = (__bf16)a0[1]; f[2] = (__bf16)a0[2]; f[3] = (__bf16)a0[3];
        f[4] = (__bf16)a1[0]; f[5] = (__bf16)a1[1]; f[6] = (__bf16)a1[2]; f[7] = (__bf16)a1[3];
        afrag[ks][tm] = f;
      }
      const int k = kb + ks * 32 + quad * 8;
#pragma unroll
      for (int tn = 0; tn < 4; tn++)
        bfrag[ks][tn] = *(const bf16x8*)(w1t + (size_t)(n0 + tn * 16 + l15) * IN_DIM + k);
    }
#pragma unroll
    for (int ks = 0; ks < 2; ks++)
#pragma unroll
      for (int tm = 0; tm < 2; tm++)
#pragma unroll
        for (int tn = 0; tn < 4; tn++)
          acc[tm][tn] = __builtin_amdgcn_mfma_f32_16x16x32_bf16(afrag[ks][tm], bfrag[ks][tn], acc[tm][tn], 0, 0, 0);
  }

#pragma unroll
  for (int tm = 0; tm < 2; tm++)
#pragma unroll
    for (int tn = 0; tn < 4; tn++) {
      const int col = n0 + tn * 16 + l15;
      const float bias = b1[col];
#pragma unroll
      for (int r = 0; r < 4; r++) {
        const int row = m0 + tm * 16 + quad * 4 + r;
        float v = acc[tm][tn][r] + bias;
        v = v > 0.0f ? v : 0.0f;
        __bf16 bv = (__bf16)v;
        h1[(size_t)row * HIDDEN + col] = __builtin_bit_cast(unsigned short, bv);
      }
    }
}

// ---------------- GEMM2: T0 = h1 @ W2 + b2 -> fp32 (fA) AND bf16 (bA) ----------------
__global__ __launch_bounds__(256) void gemm2(
    const unsigned short* __restrict__ h1, const unsigned short* __restrict__ w2t,
    const float* __restrict__ b2, float* __restrict__ t0f,
    unsigned short* __restrict__ t0b) {
  const int wave = threadIdx.x >> 6, lane = threadIdx.x & 63;
  const int m0 = blockIdx.x * 128 + wave * 32;
  if (m0 >= M_NODES) return;
  const int l15 = lane & 15, quad = lane >> 4;

  floatx4 acc[2][4] = {};
  for (int kb = 0; kb < HIDDEN; kb += 32) {
    const int k = kb + quad * 8;
    bf16x8 afrag[2], bfrag[4];
#pragma unroll
    for (int tm = 0; tm < 2; tm++)
      afrag[tm] = *(const bf16x8*)(h1 + (size_t)(m0 + tm * 16 + l15) * HIDDEN + k);
#pragma unroll
    for (int tn = 0; tn < 4; tn++)
      bfrag[tn] = *(const bf16x8*)(w2t + (size_t)(tn * 16 + l15) * HIDDEN + k);
#pragma unroll
    for (int tm = 0; tm < 2; tm++)
#pragma unroll
      for (int tn = 0; tn < 4; tn++)
        acc[tm][tn] = __builtin_amdgcn_mfma_f32_16x16x32_bf16(afrag[tm], bfrag[tn], acc[tm][tn], 0, 0, 0);
  }

#pragma unroll
  for (int tm = 0; tm < 2; tm++)
#pragma unroll
    for (int tn = 0; tn < 4; tn++) {
      const int col = tn * 16 + l15;
      const float bias = b2[col];
#pragma unroll
      for (int r = 0; r < 4; r++) {
        const int row = m0 + tm * 16 + quad * 4 + r;
        const float v = acc[tm][tn][r] + bias;
        t0f[(size_t)row * NCLS + col] = v;
        __bf16 bv = (__bf16)v;
        t0b[(size_t)row * NCLS + col] = __builtin_bit_cast(unsigned short, bv);
      }
    }
}

// ---------------- dual-row gather: 16 outstanding loads (2 independent streams) ----
__device__ __forceinline__ void row_gather2(
    const int* __restrict__ rp, const int* __restrict__ cols,
    const float* __restrict__ vals, const __bf16* __restrict__ tb,
    int r0, int r1, int c, float& out0, float& out1) {
  int e0 = rp[r0]; const int end0 = rp[r0 + 1];
  int e1 = rp[r1]; const int end1 = rp[r1 + 1];
  const int m0 = e0 + ((end0 - e0) & ~7);
  const int m1 = e1 + ((end1 - e1) & ~7);
  float a[8] = {0, 0, 0, 0, 0, 0, 0, 0};
  float b[8] = {0, 0, 0, 0, 0, 0, 0, 0};

  while (e0 < m0 && e1 < m1) {
    int ca[8], cb[8];
#pragma unroll
    for (int j = 0; j < 8; j++) { ca[j] = cols[e0 + j]; cb[j] = cols[e1 + j]; }
    float ga[8], gb[8];
#pragma unroll
    for (int j = 0; j < 8; j++) { ga[j] = (float)tb[ca[j] * NCLS + c]; gb[j] = (float)tb[cb[j] * NCLS + c]; }
#pragma unroll
    for (int j = 0; j < 8; j++) { a[j] += vals[e0 + j] * ga[j]; b[j] += vals[e1 + j] * gb[j]; }
    e0 += 8; e1 += 8;
  }
  while (e0 < m0) {
    int ca[8];
#pragma unroll
    for (int j = 0; j < 8; j++) ca[j] = cols[e0 + j];
    float ga[8];
#pragma unroll
    for (int j = 0; j < 8; j++) ga[j] = (float)tb[ca[j] * NCLS + c];
#pragma unroll
    for (int j = 0; j < 8; j++) a[j] += vals[e0 + j] * ga[j];
    e0 += 8;
  }
  while (e1 < m1) {
    int cb[8];
#pragma unroll
    for (int j = 0; j < 8; j++) cb[j] = cols[e1 + j];
    float gb[8];
#pragma unroll
    for (int j = 0; j < 8; j++) gb[j] = (float)tb[cb[j] * NCLS + c];
#pragma unroll
    for (int j = 0; j < 8; j++) b[j] += vals[e1 + j] * gb[j];
    e1 += 8;
  }
  for (; e0 < end0; ++e0) a[0] += vals[e0] * (float)tb[cols[e0] * NCLS + c];
  for (; e1 < end1; ++e1) b[0] += vals[e1] * (float)tb[cols[e1] * NCLS + c];
  out0 = ((a[0] + a[1]) + (a[2] + a[3])) + ((a[4] + a[5]) + (a[6] + a[7]));
  out1 = ((b[0] + b[1]) + (b[2] + b[3])) + ((b[4] + b[5]) + (b[6] + b[7]));
}

// ---------------- SpMM first: T1 = L T0 ; z = g0*T0 + g1*T1 ----------------
// wave handles rows r0, r0+1. block = 4 waves = 8 rows. grid = 12500.
__global__ __launch_bounds__(256) void spmm_first(
    const int* __restrict__ rp, const int* __restrict__ cols,
    const float* __restrict__ vals, const __bf16* __restrict__ t0b,
    const float* __restrict__ t0f, float* __restrict__ t1f,
    unsigned short* __restrict__ t1b, const float* __restrict__ gamma,
    float* __restrict__ z) {
  const int r0 = blockIdx.x * 8 + (threadIdx.x >> 6) * 2;
  const int r1 = r0 + 1;
  const int c = threadIdx.x & 63;
  float s0, s1;
  row_gather2(rp, cols, vals, t0b, r0, r1, c, s0, s1);
  const float g0 = gamma[0], g1 = gamma[1];
  const size_t o0 = (size_t)r0 * NCLS + c;
  const size_t o1 = (size_t)r1 * NCLS + c;
  t1f[o0] = s0;
  t1f[o1] = s1;
  __bf16 bv0 = (__bf16)s0, bv1 = (__bf16)s1;
  t1b[o0] = __builtin_bit_cast(unsigned short, bv0);
  t1b[o1] = __builtin_bit_cast(unsigned short, bv1);
  z[o0] = g0 * t0f[o0] + g1 * s0;
  z[o1] = g0 * t0f[o1] + g1 * s1;
}

// ---------------- SpMM step: Tn = 2 L Tc - Tp (in place over Tp); z += g[k]*Tn ----
__global__ __launch_bounds__(256) void spmm_step(
    const int* __restrict__ rp, const int* __restrict__ cols,
    const float* __restrict__ vals, const __bf16* __restrict__ tcb,
    float* __restrict__ tpf, unsigned short* __restrict__ tnb,
    const float* __restrict__ gamma, int kidx, float* __restrict__ z) {
  const int r0 = blockIdx.x * 8 + (threadIdx.x >> 6) * 2;
  const int r1 = r0 + 1;
  const int c = threadIdx.x & 63;
  float s0, s1;
  row_gather2(rp, cols, vals, tcb, r0, r1, c, s0, s1);
  const float gk = gamma[kidx];
  const size_t o0 = (size_t)r0 * NCLS + c;
  const size_t o1 = (size_t)r1 * NCLS + c;
  const float tn0 = 2.0f * s0 - tpf[o0];
  const float tn1 = 2.0f * s1 - tpf[o1];
  tpf[o0] = tn0;
  tpf[o1] = tn1;
  __bf16 bv0 = (__bf16)tn0, bv1 = (__bf16)tn1;
  tnb[o0] = __builtin_bit_cast(unsigned short, bv0);
  tnb[o1] = __builtin_bit_cast(unsigned short, bv1);
  z[o0] += gk * tn0;
  z[o1] += gk * tn1;
}

extern "C" void kernel_launch(void* const* d_in, const int* in_sizes, int n_in,
                              void* d_out, int out_size, void* d_ws, size_t ws_size,
                              hipStream_t stream) {
  const float* x     = (const float*)d_in[0];
  const int*   erow  = (const int*)d_in[1];
  const int*   ecol  = (const int*)d_in[2];
  const float* evals = (const float*)d_in[3];
  const float* W1    = (const float*)d_in[4];
  const float* b1    = (const float*)d_in[5];
  const float* W2    = (const float*)d_in[6];
  const float* b2    = (const float*)d_in[7];
  const float* gamma = (const float*)d_in[8];

  char* ws = (char*)d_ws;
  int*            rp  = (int*)(ws + WS_ROWPTR);
  unsigned short* w1t = (unsigned short*)(ws + WS_W1T);
  unsigned short* w2t = (unsigned short*)(ws + WS_W2T);
  unsigned short* h1  = (unsigned short*)(ws + WS_H1);
  float*          fA  = (float*)(ws + WS_FA);
  float*          fB  = (float*)(ws + WS_FB);
  unsigned short* bA  = (unsigned short*)(ws + WS_BA);
  unsigned short* bB  = (unsigned short*)(ws + WS_BB);  // aliases h1 (dead after gemm2)
  float*          z   = (float*)d_out;

  prep_weights<<<576, 256, 0, stream>>>(W1, W2, w1t, w2t);
  build_rowptr<<<(M_NODES + 256) / 256, 256, 0, stream>>>(erow, rp);
  gemm1<<<M_NODES / 32, 256, 0, stream>>>(x, w1t, b1, h1);
  gemm2<<<(M_NODES + 127) / 128, 256, 0, stream>>>(h1, w2t, b2, fA, bA);

  spmm_first<<<M_NODES / 8, 256, 0, stream>>>(rp, ecol, evals, (const __bf16*)bA,
                                              fA, fB, bB, gamma, z);

  float*          fprev = fA;
  float*          fothr = fB;
  unsigned short* bcur  = bB;
  unsigned short* bnext = bA;
  for (int k = 2; k <= 8; ++k) {
    spmm_step<<<M_NODES / 8, 256, 0, stream>>>(rp, ecol, evals, (const __bf16*)bcur,
                                               fprev, bnext, gamma, k, z);
    float* tf = fprev; fprev = fothr; fothr = tf;
    unsigned short* tb = bcur; bcur = bnext; bnext = tb;
  }
}